// Round 3
// 185.928 us; speedup vs baseline: 1.0459x; 1.0459x over previous
//
#include <hip/hip_runtime.h>

// GCN_72988674228318: 2-layer GCN on MI355X.
// R17 (2nd resubmit -- two consecutive infra failures, no counters yet):
// fuse bucket_direct INTO gemm1 as a homogeneous per-block prologue
// (R15's failure was heterogeneous block types: bucket-only blocks holding
// 52KB LDS co-scheduled against MFMA blocks). Every gemm1 block now handles
// 768 edges (3/thread, independent atomics for MLP); atomic latency drains
// under the W/X staging loads + f2bf, scatter tail hides under MFMA.
// This breaks gemm1's cnt dependency -> A1b stored UNSCALED; agg1 applies
// dinv[src] per edge (rsqrtf(cnt[s]+1), broadcast load from hot cnt table).
// Layer 2 keeps the proven pre-scaled scheme (cnt final by then).
// 5 launches: prep0, gemm1_bucket, agg1, gemm2, agg2.

#define NN      50000
#define INC     128
#define HIDC    128
#define OUTC    64
#define NE      600000
#define NB      ((NN + 255) / 256)   // 196 zero blocks
#define CAP     64                   // bucket capacity per node

typedef unsigned short bf16_t;
typedef short bf16x8 __attribute__((ext_vector_type(8)));
typedef float f32x4  __attribute__((ext_vector_type(4)));

__device__ __forceinline__ unsigned short f2bf(float f) {
  unsigned u = __float_as_uint(f);
  u += 0x7fffu + ((u >> 16) & 1u);   // round to nearest even
  return (unsigned short)(u >> 16);
}

__device__ __forceinline__ float dinv_of(int c) {
  return 1.0f / sqrtf((float)(c + 1));
}

// ---------------- Threefry-2x32, key = (0, 42); partitionable path ---------
__device__ __forceinline__ void tf_round(unsigned &x0, unsigned &x1, int r) {
  x0 += x1;
  x1 = (x1 << r) | (x1 >> (32 - r));
  x1 ^= x0;
}

__device__ __forceinline__ void threefry_0_42(unsigned &x0, unsigned &x1) {
  const unsigned ks0 = 0u, ks1 = 42u, ks2 = 0x1BD11BDAu ^ 42u;
  x0 += ks0; x1 += ks1;
  tf_round(x0,x1,13); tf_round(x0,x1,15); tf_round(x0,x1,26); tf_round(x0,x1, 6);
  x0 += ks1; x1 += ks2 + 1u;
  tf_round(x0,x1,17); tf_round(x0,x1,29); tf_round(x0,x1,16); tf_round(x0,x1,24);
  x0 += ks2; x1 += ks0 + 2u;
  tf_round(x0,x1,13); tf_round(x0,x1,15); tf_round(x0,x1,26); tf_round(x0,x1, 6);
  x0 += ks0; x1 += ks1 + 3u;
  tf_round(x0,x1,17); tf_round(x0,x1,29); tf_round(x0,x1,16); tf_round(x0,x1,24);
  x0 += ks1; x1 += ks2 + 4u;
  tf_round(x0,x1,13); tf_round(x0,x1,15); tf_round(x0,x1,26); tf_round(x0,x1, 6);
  x0 += ks2; x1 += ks0 + 5u;
}

__device__ __forceinline__ bool keep_bit(unsigned idx) {
  unsigned x0 = 0u, x1 = idx;
  threefry_0_42(x0, x1);
  return ((x0 ^ x1) & 0x80000000u) == 0u;
}

// ---------------- prep0: zero cnt (NB blocks) + dtype detect (1 block) ------
__global__ __launch_bounds__(256)
void prep0(const unsigned* __restrict__ ew, int* __restrict__ flag,
           int* __restrict__ cnt) {
  const int b = blockIdx.x, t = threadIdx.x;
  if (b < NB) {
    int idx = b * 256 + t;
    if (idx < NN) cnt[idx] = 0;
  } else {
    __shared__ unsigned acc[256];
    unsigned v = 0;
    for (int i = t; i < 2048; i += 256) v |= ew[2 * i + 1];
    acc[t] = v;
    __syncthreads();
    for (int s = 128; s > 0; s >>= 1) {
      if (t < s) acc[t] |= acc[t + s];
      __syncthreads();
    }
    if (t == 0) *flag = (acc[0] == 0u) ? 1 : 0;   // 1 => int64
  }
}

// ---------------- gemm1_bucket: fused edge bucketing + layer-1 GEMM ---------
// A1b = bf16(X @ W1)  (UNSCALED -- dinv applied in agg1).
// Edge prologue: 768 edges/block, 3/thread; atomics issued before staging so
// the L2 round-trip drains under ~100KB of staging loads + f2bf VALU work.
__global__ __launch_bounds__(256, 3)
void gemm1_bucket(const float* __restrict__ X, const float* __restrict__ W,
                  const void* __restrict__ ei, const int* __restrict__ flag,
                  int* __restrict__ cnt, int* __restrict__ ssrc,
                  bf16_t* __restrict__ Ab) {
  constexpr int C  = HIDC;
  constexpr int K  = 128;
  constexpr int KS = 136;
  constexpr int CT16 = C / 16;
  __shared__ bf16_t xs[64 * KS];
  __shared__ bf16_t wsT[C * KS];

  const int tid = threadIdx.x;
  const int rb  = blockIdx.x * 64;

  // --- edge loads: 3 independent edges per thread ---
  const int eb = blockIdx.x * 768;
  int es[3], ed[3];
  bool ev[3];
  const bool i64 = (*flag != 0);
#pragma unroll
  for (int j = 0; j < 3; j++) {
    int e = eb + j * 256 + tid;
    ev[j] = (e < NE);
    es[j] = 0; ed[j] = 0;
    if (ev[j]) {
      if (i64) {
        es[j] = (int)((const long long*)ei)[e];
        ed[j] = (int)((const long long*)ei)[NE + e];
      } else {
        es[j] = ((const int*)ei)[e];
        ed[j] = ((const int*)ei)[NE + e];
      }
    }
  }
  // issue the returning atomics NOW; their latency hides under staging below
  int slot[3];
#pragma unroll
  for (int j = 0; j < 3; j++)
    slot[j] = ev[j] ? atomicAdd(&cnt[ed[j]], 1) : CAP;

  // --- staging: W (f32 -> bf16, transposed) and X (f32 -> bf16) into LDS ---
  for (int i = tid; i < C * (K / 8); i += 256) {
    int nn = i % C, kc = i / C;
    ushort4 lo, hi;
    lo.x = f2bf(W[(size_t)(kc * 8 + 0) * C + nn]);
    lo.y = f2bf(W[(size_t)(kc * 8 + 1) * C + nn]);
    lo.z = f2bf(W[(size_t)(kc * 8 + 2) * C + nn]);
    lo.w = f2bf(W[(size_t)(kc * 8 + 3) * C + nn]);
    hi.x = f2bf(W[(size_t)(kc * 8 + 4) * C + nn]);
    hi.y = f2bf(W[(size_t)(kc * 8 + 5) * C + nn]);
    hi.z = f2bf(W[(size_t)(kc * 8 + 6) * C + nn]);
    hi.w = f2bf(W[(size_t)(kc * 8 + 7) * C + nn]);
    *(ushort4*)&wsT[nn * KS + kc * 8]     = lo;
    *(ushort4*)&wsT[nn * KS + kc * 8 + 4] = hi;
  }
  for (int i = tid; i < 64 * (K / 4); i += 256) {
    int r = i >> 5, kq = i & 31;
    int row = rb + r;
    ushort4 o = make_ushort4(0, 0, 0, 0);
    if (row < NN) {
      float4 v = *(const float4*)(X + (size_t)row * K + kq * 4);
      o.x = f2bf(v.x); o.y = f2bf(v.y); o.z = f2bf(v.z); o.w = f2bf(v.w);
    }
    *(ushort4*)&xs[r * KS + kq * 4] = o;
  }

  // --- scatter (consumes atomic results; store tail hides under MFMA) ---
#pragma unroll
  for (int j = 0; j < 3; j++)
    if (ev[j] && slot[j] < CAP) ssrc[ed[j] * CAP + slot[j]] = es[j];

  __syncthreads();

  const int wv   = tid >> 6;
  const int lane = tid & 63;
  const int m    = lane & 15;
  const int q    = lane >> 4;

  f32x4 acc[CT16];
#pragma unroll
  for (int c = 0; c < CT16; c++) acc[c] = (f32x4){0.f, 0.f, 0.f, 0.f};

#pragma unroll
  for (int k0 = 0; k0 < K; k0 += 32) {
    bf16x8 a = *(bf16x8*)&xs[(wv * 16 + m) * KS + k0 + q * 8];
#pragma unroll
    for (int c = 0; c < CT16; c++) {
      bf16x8 b = *(bf16x8*)&wsT[(c * 16 + m) * KS + k0 + q * 8];
      acc[c] = __builtin_amdgcn_mfma_f32_16x16x32_bf16(a, b, acc[c], 0, 0, 0);
    }
  }

  const int rowq = rb + wv * 16 + q * 4;
#pragma unroll
  for (int r = 0; r < 4; r++) {
    int row = rowq + r;
    if (row < NN) {
#pragma unroll
      for (int c = 0; c < CT16; c++)
        Ab[(size_t)row * C + c * 16 + m] = f2bf(acc[c][r]);   // unscaled
    }
  }
}

// ---------------- MFMA GEMM (layer 2): Ab = bf16((X @ W) * dinv[row]) -------
template<int C, bool IN_BF16>
__global__ __launch_bounds__(256, 3)
void gemm_mfma(const void* __restrict__ Xv, const float* __restrict__ W,
               const int* __restrict__ cnt, bf16_t* __restrict__ Ab, int n) {
  constexpr int K  = 128;
  constexpr int KS = 136;
  constexpr int CT16 = C / 16;
  __shared__ bf16_t xs[64 * KS];
  __shared__ bf16_t wsT[C * KS];

  const int tid = threadIdx.x;
  const int rb  = blockIdx.x * 64;

  for (int i = tid; i < C * (K / 8); i += 256) {
    int nn = i % C, kc = i / C;
    ushort4 lo, hi;
    lo.x = f2bf(W[(size_t)(kc * 8 + 0) * C + nn]);
    lo.y = f2bf(W[(size_t)(kc * 8 + 1) * C + nn]);
    lo.z = f2bf(W[(size_t)(kc * 8 + 2) * C + nn]);
    lo.w = f2bf(W[(size_t)(kc * 8 + 3) * C + nn]);
    hi.x = f2bf(W[(size_t)(kc * 8 + 4) * C + nn]);
    hi.y = f2bf(W[(size_t)(kc * 8 + 5) * C + nn]);
    hi.z = f2bf(W[(size_t)(kc * 8 + 6) * C + nn]);
    hi.w = f2bf(W[(size_t)(kc * 8 + 7) * C + nn]);
    *(ushort4*)&wsT[nn * KS + kc * 8]     = lo;
    *(ushort4*)&wsT[nn * KS + kc * 8 + 4] = hi;
  }
  for (int i = tid; i < 64 * (K / 4); i += 256) {
    int r = i >> 5, kq = i & 31;
    int row = rb + r;
    ushort4 o = make_ushort4(0, 0, 0, 0);
    if (row < n) {
      if (IN_BF16) {
        o = *(const ushort4*)((const bf16_t*)Xv + (size_t)row * K + kq * 4);
      } else {
        float4 v = *(const float4*)((const float*)Xv + (size_t)row * K + kq * 4);
        o.x = f2bf(v.x); o.y = f2bf(v.y); o.z = f2bf(v.z); o.w = f2bf(v.w);
      }
    }
    *(ushort4*)&xs[r * KS + kq * 4] = o;
  }
  __syncthreads();

  const int wv   = tid >> 6;
  const int lane = tid & 63;
  const int m    = lane & 15;
  const int q    = lane >> 4;

  f32x4 acc[CT16];
#pragma unroll
  for (int c = 0; c < CT16; c++) acc[c] = (f32x4){0.f, 0.f, 0.f, 0.f};

#pragma unroll
  for (int k0 = 0; k0 < K; k0 += 32) {
    bf16x8 a = *(bf16x8*)&xs[(wv * 16 + m) * KS + k0 + q * 8];
#pragma unroll
    for (int c = 0; c < CT16; c++) {
      bf16x8 b = *(bf16x8*)&wsT[(c * 16 + m) * KS + k0 + q * 8];
      acc[c] = __builtin_amdgcn_mfma_f32_16x16x32_bf16(a, b, acc[c], 0, 0, 0);
    }
  }

  const int rowq = rb + wv * 16 + q * 4;
#pragma unroll
  for (int r = 0; r < 4; r++) {
    int row = rowq + r;
    if (row < n) {
      float dv = dinv_of(cnt[row]);
#pragma unroll
      for (int c = 0; c < CT16; c++)
        Ab[(size_t)row * C + c * 16 + m] = f2bf(acc[c][r] * dv);
    }
  }
}

__device__ __forceinline__ void acc_u2(float4 &a, uint2 v) {
  a.x += __uint_as_float(v.x << 16);
  a.y += __uint_as_float(v.x & 0xffff0000u);
  a.z += __uint_as_float(v.y << 16);
  a.w += __uint_as_float(v.y & 0xffff0000u);
}

// scaled accumulate: a += dv * bf16row
__device__ __forceinline__ void acc_u2s(float4 &a, uint2 v, float dv) {
  a.x = fmaf(dv, __uint_as_float(v.x << 16),         a.x);
  a.y = fmaf(dv, __uint_as_float(v.x & 0xffff0000u), a.y);
  a.z = fmaf(dv, __uint_as_float(v.y << 16),         a.z);
  a.w = fmaf(dv, __uint_as_float(v.y & 0xffff0000u), a.w);
}

__device__ __forceinline__ float dinv_fast(int c) {
  return rsqrtf((float)(c + 1));   // 1-instr v_rsq; bf16 rounding dominates err
}

// ---------------- agg1: half-wave/node bf16 gather -> Hb (bf16) -------------
// A1b rows UNSCALED: multiply each gathered row by dinv[src] (broadcast cnt
// load from hot 200KB table + v_rsq -- negligible vs the 256B row gather).
__global__ __launch_bounds__(256)
void agg1(const bf16_t* __restrict__ A1b, const int* __restrict__ cnt,
          const int* __restrict__ ssrc, const float* __restrict__ b1,
          bf16_t* __restrict__ Hb) {
  int node = (blockIdx.x * 256 + threadIdx.x) >> 5;
  int lane = threadIdx.x & 31;
  if (node >= NN) return;

  const uint2* A4 = (const uint2*)A1b;
  const int cn = cnt[node];
  const float dn = dinv_of(cn);
  float4 acc = make_float4(0.f, 0.f, 0.f, 0.f);
  acc_u2s(acc, A4[(size_t)node * 32 + lane], dn);   // self-loop: A[n]*dn
  int e = node * CAP;
  int end = e + min(cn, CAP);
  for (; e + 3 < end; e += 4) {
    int s0 = ssrc[e], s1 = ssrc[e+1], s2 = ssrc[e+2], s3 = ssrc[e+3];
    uint2 v0 = A4[(size_t)s0 * 32 + lane];
    uint2 v1 = A4[(size_t)s1 * 32 + lane];
    uint2 v2 = A4[(size_t)s2 * 32 + lane];
    uint2 v3 = A4[(size_t)s3 * 32 + lane];
    float q0 = dinv_fast(cnt[s0]);
    float q1 = dinv_fast(cnt[s1]);
    float q2 = dinv_fast(cnt[s2]);
    float q3 = dinv_fast(cnt[s3]);
    acc_u2s(acc, v0, q0); acc_u2s(acc, v1, q1);
    acc_u2s(acc, v2, q2); acc_u2s(acc, v3, q3);
  }
  for (; e < end; e++) {
    int s = ssrc[e];
    acc_u2s(acc, A4[(size_t)s * 32 + lane], dinv_fast(cnt[s]));
  }

  int col = lane * 4;
  float4 bb = *(const float4*)&b1[col];
  float h0 = fmaxf(acc.x * dn + bb.x, 0.f);
  float h1 = fmaxf(acc.y * dn + bb.y, 0.f);
  float h2 = fmaxf(acc.z * dn + bb.z, 0.f);
  float h3 = fmaxf(acc.w * dn + bb.w, 0.f);
  unsigned base = (unsigned)node * HIDC + (unsigned)col;
  ushort4 o;
  o.x = keep_bit(base)     ? f2bf(2.f * h0) : 0;
  o.y = keep_bit(base + 1) ? f2bf(2.f * h1) : 0;
  o.z = keep_bit(base + 2) ? f2bf(2.f * h2) : 0;
  o.w = keep_bit(base + 3) ? f2bf(2.f * h3) : 0;
  ((ushort4*)Hb)[(size_t)node * 32 + lane] = o;
}

// ---------------- agg2: quarter-wave/node bf16 gather + bias -> d_out -------
__global__ __launch_bounds__(256)
void agg2(const bf16_t* __restrict__ A2b, const int* __restrict__ cnt,
          const int* __restrict__ ssrc, const float* __restrict__ b2,
          float* __restrict__ out) {
  int node = (blockIdx.x * 256 + threadIdx.x) >> 4;
  int lane = threadIdx.x & 15;
  if (node >= NN) return;

  const uint2* A4 = (const uint2*)A2b;
  const int cn = cnt[node];
  const float dn = dinv_of(cn);
  float4 acc = make_float4(0.f, 0.f, 0.f, 0.f);
  acc_u2(acc, A4[(size_t)node * 16 + lane]);
  int e = node * CAP;
  int end = e + min(cn, CAP);
  for (; e + 3 < end; e += 4) {
    int s0 = ssrc[e], s1 = ssrc[e+1], s2 = ssrc[e+2], s3 = ssrc[e+3];
    uint2 v0 = A4[(size_t)s0 * 16 + lane];
    uint2 v1 = A4[(size_t)s1 * 16 + lane];
    uint2 v2 = A4[(size_t)s2 * 16 + lane];
    uint2 v3 = A4[(size_t)s3 * 16 + lane];
    acc_u2(acc, v0); acc_u2(acc, v1); acc_u2(acc, v2); acc_u2(acc, v3);
  }
  for (; e < end; e++)
    acc_u2(acc, A4[(size_t)ssrc[e] * 16 + lane]);

  float4 bb = *(const float4*)&b2[lane * 4];
  ((float4*)out)[(size_t)node * 16 + lane] =
    make_float4(acc.x*dn + bb.x, acc.y*dn + bb.y, acc.z*dn + bb.z, acc.w*dn + bb.w);
}

// ---------------------------------------------------------------------------
extern "C" void kernel_launch(void* const* d_in, const int* in_sizes, int n_in,
                              void* d_out, int out_size, void* d_ws, size_t ws_size,
                              hipStream_t stream) {
  const float* x  = (const float*)d_in[0];
  const float* W1 = (const float*)d_in[1];
  const float* b1 = (const float*)d_in[2];
  const float* W2 = (const float*)d_in[3];
  const float* b2 = (const float*)d_in[4];
  const void*  ei = d_in[5];
  float* out = (float*)d_out;

  int*    flag = (int*)d_ws;               // 64
  int*    cnt  = flag + 64;                // 50048
  int*    ssrc = cnt + 50048;              // 3.2M (50000*64)
  bf16_t* A1b  = (bf16_t*)(ssrc + NN * CAP);   // 6.4M bf16
  bf16_t* Hb   = A1b + 6400000;                // 6.4M bf16
  bf16_t* A2b  = Hb + 6400000;                 // 3.2M bf16

  // 0. zero cnt + dtype detect (parallel blocks)
  prep0<<<NB + 1, 256, 0, stream>>>((const unsigned*)ei, flag, cnt);

  const int rtiles = (NN + 63) / 64;   // 782

  // 1. layer-1 GEMM fused with edge bucketing (782 blocks x 768 edges)
  gemm1_bucket<<<rtiles, 256, 0, stream>>>(x, W1, ei, flag, cnt, ssrc, A1b);
  agg1<<<(NN * 32 + 255) / 256, 256, 0, stream>>>(A1b, cnt, ssrc, b1, Hb);

  // 2. layer 2 (cnt final: keep pre-scaled scheme)
  gemm_mfma<OUTC, true><<<rtiles, 256, 0, stream>>>(Hb, W2, cnt, A2b, NN);
  agg2<<<(NN * 16 + 255) / 256, 256, 0, stream>>>(A2b, cnt, ssrc, b2, out);
}